// Round 7
// baseline (1013.229 us; speedup 1.0000x reference)
//
#include <hip/hip_runtime.h>
#include <hip/hip_fp16.h>

#define NDRUG 20000
#define NTGT  20000
#define NN    40000
#define NE    500000
#define DDIM  128
#define CAP   96

typedef __attribute__((ext_vector_type(4))) float f32x4;
typedef __attribute__((ext_vector_type(8))) short s16x8;

__device__ inline unsigned short bf_rn(float x) {
  unsigned u = __float_as_uint(x);
  return (unsigned short)((u + 0x7FFFu + ((u >> 16) & 1u)) >> 16);
}
__device__ inline float bf_f(unsigned short h) {
  return __uint_as_float(((unsigned)h) << 16);
}
// fp32 -> bf16 hi (RTN) + lo (truncated residual)
__device__ __forceinline__ void split1(float x, short& h, short& l) {
  const unsigned u = __float_as_uint(x);
  const unsigned hu = (u + 0x7FFFu + ((u >> 16) & 1u)) & 0xFFFF0000u;
  h = (short)(hu >> 16);
  l = (short)(__float_as_uint(x - __uint_as_float(hu)) >> 16);
}
__device__ __forceinline__ void conv8(const f32x4& a0, const f32x4& a1,
                                      s16x8& ah, s16x8& al) {
#pragma unroll
  for (int j = 0; j < 4; ++j) {
    short h, l;
    split1(a0[j], h, l); ah[j] = h; al[j] = l;
    split1(a1[j], h, l); ah[j + 4] = h; al[j + 4] = l;
  }
}
__device__ __forceinline__ void mfma3(const s16x8& ah, const s16x8& al,
                                      const s16x8 bh[4], const s16x8 bl[4],
                                      f32x4 acc[4]) {
#pragma unroll
  for (int n = 0; n < 4; ++n) {
    acc[n] = __builtin_amdgcn_mfma_f32_16x16x32_bf16(ah, bh[n], acc[n], 0, 0, 0);
    acc[n] = __builtin_amdgcn_mfma_f32_16x16x32_bf16(ah, bl[n], acc[n], 0, 0, 0);
    acc[n] = __builtin_amdgcn_mfma_f32_16x16x32_bf16(al, bh[n], acc[n], 0, 0, 0);
  }
}

// ------- weight prep: W [K][128] fp32 -> Wt_hi/Wt_lo [128][K] bf16; grid.y batches -------
__global__ void prep_w(const float* __restrict__ W, short* __restrict__ hi,
                       short* __restrict__ lo, int K) {
  const size_t mat = (size_t)blockIdx.y * K * 128;
  const int idx = blockIdx.x * blockDim.x + threadIdx.x;
  if (idx >= K * 128) return;
  const int k = idx >> 7, c = idx & 127;
  const float x = W[mat + idx];
  const unsigned short h = bf_rn(x);
  hi[mat + (size_t)c * K + k] = (short)h;
  lo[mat + (size_t)c * K + k] = (short)bf_rn(x - bf_f(h));
}

// ---------------- LDS-free projection GEMM w/ register double-buffer ----------------
// BM=64 x BN=64; 4 waves, each owns 16 rows x 64 cols. No LDS, no barriers.
// Per K-step: prefetch next {A 2xf32x4, B 8xs16x8} while MFMA'ing current.
__global__ __launch_bounds__(256)
void gemm_proj(const float* __restrict__ xd, const short* __restrict__ wdh,
               const short* __restrict__ wdl, const float* __restrict__ bd,
               const float* __restrict__ xt, const short* __restrict__ wth,
               const short* __restrict__ wtl, const float* __restrict__ bt,
               short* __restrict__ hh, short* __restrict__ hl) {
  int b = blockIdx.x;
  const float* A; const short* WH; const short* WL; const float* bias;
  int M, K, rowbase;
  if (b < 626) { A = xd; WH = wdh; WL = wdl; bias = bd; M = NDRUG; K = 2048; rowbase = 0; }
  else { b -= 626; A = xt; WH = wth; WL = wtl; bias = bt; M = NTGT; K = 1280; rowbase = NDRUG; }
  const int bm = (b >> 1) * 64;
  const int bn = (b & 1) * 64;
  const int w = threadIdx.x >> 6, lane = threadIdx.x & 63;
  const int lr = lane & 15, kg = lane >> 4;

  int arow = bm + w * 16 + lr; if (arow >= M) arow = M - 1;
  const float* ap = A + (size_t)arow * K + kg * 8;
  const short* wph = WH + (size_t)(bn + lr) * K + kg * 8;
  const short* wpl = WL + (size_t)(bn + lr) * K + kg * 8;
  const size_t kstep = (size_t)16 * K;

  f32x4 acc[4] = {};

  // preload step 0
  f32x4 ca0 = *(const f32x4*)ap;
  f32x4 ca1 = *(const f32x4*)(ap + 4);
  s16x8 cbh[4], cbl[4];
#pragma unroll
  for (int n = 0; n < 4; ++n) {
    cbh[n] = *(const s16x8*)(wph + n * kstep);
    cbl[n] = *(const s16x8*)(wpl + n * kstep);
  }

  const int steps = K >> 5;
  for (int s = 1; s < steps; ++s) {
    ap += 32; wph += 32; wpl += 32;
    // issue next-step loads first (overlap with MFMA below)
    const f32x4 na0 = *(const f32x4*)ap;
    const f32x4 na1 = *(const f32x4*)(ap + 4);
    s16x8 nbh[4], nbl[4];
#pragma unroll
    for (int n = 0; n < 4; ++n) {
      nbh[n] = *(const s16x8*)(wph + n * kstep);
      nbl[n] = *(const s16x8*)(wpl + n * kstep);
    }
    s16x8 ah, al;
    conv8(ca0, ca1, ah, al);
    mfma3(ah, al, cbh, cbl, acc);
    ca0 = na0; ca1 = na1;
#pragma unroll
    for (int n = 0; n < 4; ++n) { cbh[n] = nbh[n]; cbl[n] = nbl[n]; }
  }
  {
    s16x8 ah, al;
    conv8(ca0, ca1, ah, al);
    mfma3(ah, al, cbh, cbl, acc);
  }

#pragma unroll
  for (int n = 0; n < 4; ++n) {
    const int col = bn + n * 16 + lr;
    const float bv = bias[col];
#pragma unroll
    for (int r = 0; r < 4; ++r) {
      const int row = bm + w * 16 + kg * 4 + r;
      if (row < M) {
        short h, l;
        split1(acc[n][r] + bv, h, l);
        hh[(size_t)(rowbase + row) * DDIM + col] = h;
        hl[(size_t)(rowbase + row) * DDIM + col] = l;
      }
    }
  }
}

// ---------------- LDS-free GAT GEMM (bf16-plane A) w/ reg double-buffer ----------------
// BM=64 x BN=64 per block; grid (625*2, 3). hp fp16 [rel][NN][128]; fused s/d halves.
__global__ __launch_bounds__(256)
void gemm_gat(const short* __restrict__ ahh, const short* __restrict__ ahl,
              const short* __restrict__ WtH3, const short* __restrict__ WtL3,
              const float* __restrict__ asrc3, const float* __restrict__ adst3,
              __half* __restrict__ hp16, float* __restrict__ s_half,
              float* __restrict__ d_half) {
  const int rel = blockIdx.y;
  const int half = blockIdx.x & 1;
  const int bm = (blockIdx.x >> 1) * 64;
  const int bn = half * 64;
  const short* WH = WtH3 + (size_t)rel * DDIM * DDIM;
  const short* WL = WtL3 + (size_t)rel * DDIM * DDIM;
  const int w = threadIdx.x >> 6, lane = threadIdx.x & 63;
  const int lr = lane & 15, kg = lane >> 4;

  const int arow = bm + w * 16 + lr;
  const short* aph = ahh + (size_t)arow * DDIM + kg * 8;
  const short* apl = ahl + (size_t)arow * DDIM + kg * 8;
  const short* wph = WH + (size_t)(bn + lr) * DDIM + kg * 8;
  const short* wpl = WL + (size_t)(bn + lr) * DDIM + kg * 8;

  f32x4 acc[4] = {};

  s16x8 cah = *(const s16x8*)aph;
  s16x8 cal = *(const s16x8*)apl;
  s16x8 cbh[4], cbl[4];
#pragma unroll
  for (int n = 0; n < 4; ++n) {
    cbh[n] = *(const s16x8*)(wph + n * 16 * DDIM);
    cbl[n] = *(const s16x8*)(wpl + n * 16 * DDIM);
  }

#pragma unroll
  for (int s = 1; s <= 3; ++s) {
    const s16x8 nah = *(const s16x8*)(aph + s * 32);
    const s16x8 nal = *(const s16x8*)(apl + s * 32);
    s16x8 nbh[4], nbl[4];
#pragma unroll
    for (int n = 0; n < 4; ++n) {
      nbh[n] = *(const s16x8*)(wph + s * 32 + n * 16 * DDIM);
      nbl[n] = *(const s16x8*)(wpl + s * 32 + n * 16 * DDIM);
    }
    mfma3(cah, cal, cbh, cbl, acc);
    cah = nah; cal = nal;
#pragma unroll
    for (int n = 0; n < 4; ++n) { cbh[n] = nbh[n]; cbl[n] = nbl[n]; }
  }
  mfma3(cah, cal, cbh, cbl, acc);

  // hp fp16 write
  __half* hpr = hp16 + ((size_t)rel * NN) * DDIM;
#pragma unroll
  for (int n = 0; n < 4; ++n) {
    const int col = bn + n * 16 + lr;
#pragma unroll
    for (int r = 0; r < 4; ++r) {
      const int row = bm + w * 16 + kg * 4 + r;
      hpr[(size_t)row * DDIM + col] = __float2half_rn(acc[n][r]);
    }
  }
  // fused s/d partials (this col-half's contribution)
  float asv[4], adv[4];
#pragma unroll
  for (int n = 0; n < 4; ++n) {
    asv[n] = asrc3[rel * DDIM + bn + n * 16 + lr];
    adv[n] = adst3[rel * DDIM + bn + n * 16 + lr];
  }
#pragma unroll
  for (int r = 0; r < 4; ++r) {
    float ps = 0.f, pd = 0.f;
#pragma unroll
    for (int n = 0; n < 4; ++n) { ps += acc[n][r] * asv[n]; pd += acc[n][r] * adv[n]; }
#pragma unroll
    for (int o = 1; o < 16; o <<= 1) { ps += __shfl_xor(ps, o); pd += __shfl_xor(pd, o); }
    if (lr == 0) {
      const int row = bm + w * 16 + kg * 4 + r;
      s_half[(size_t)(half * 3 + rel) * NN + row] = ps;
      d_half[(size_t)(half * 3 + rel) * NN + row] = pd;
    }
  }
}

// ------------- edge bias for BOTH layers, float2 loads -------------
__global__ __launch_bounds__(256)
void edge_bias_kernel(const float* __restrict__ ea, const float* __restrict__ ae0,
                      const float* __restrict__ ae1, float* __restrict__ b0,
                      float* __restrict__ b1) {
  const int wave = threadIdx.x >> 6, lane = threadIdx.x & 63;
  const int e = blockIdx.x * 4 + wave;
  if (e >= NE) return;
  const float2 v = *(const float2*)(ea + (size_t)e * DDIM + (lane << 1));
  float s0 = v.x * ae0[lane << 1] + v.y * ae0[(lane << 1) + 1];
  float s1 = v.x * ae1[lane << 1] + v.y * ae1[(lane << 1) + 1];
#pragma unroll
  for (int o = 32; o; o >>= 1) { s0 += __shfl_xor(s0, o); s1 += __shfl_xor(s1, o); }
  if (lane == 0) { b0[e] = s0; b1[e] = s1; }
}

// ------------- CSR build (3 relations batched) -------------
__global__ void count3(const int* __restrict__ d0, const int* __restrict__ d1,
                       const int* __restrict__ d2, int* __restrict__ counts) {
  const int rel = blockIdx.y;
  const int* dst = rel == 0 ? d0 : (rel == 1 ? d1 : d2);
  int* c = counts + rel * NN;
  for (int e = blockIdx.x * blockDim.x + threadIdx.x; e < NE; e += gridDim.x * blockDim.x)
    atomicAdd(&c[dst[e]], 1);
}

__global__ __launch_bounds__(1024)
void scan3(const int* __restrict__ counts_all, int* __restrict__ offs_all,
           int* __restrict__ cursor_all) {
  const int rel = blockIdx.x;
  const int* counts = counts_all + rel * NN;
  int* offs = offs_all + rel * (NN + 1);
  int* cursor = cursor_all + rel * (NN + 1);
  __shared__ int part[1024];
  const int t = threadIdx.x;
  const int CH = 40;
  const int base = t * CH;
  const int lim = min(base + CH, NN);
  int sum = 0;
  for (int i = base; i < lim; ++i) sum += counts[i];
  part[t] = sum;
  __syncthreads();
  for (int o = 1; o < 1024; o <<= 1) {
    const int v = (t >= o) ? part[t - o] : 0;
    __syncthreads();
    part[t] += v;
    __syncthreads();
  }
  int run = (t == 0) ? 0 : part[t - 1];
  for (int i = base; i < lim; ++i) { offs[i] = run; cursor[i] = run; run += counts[i]; }
  if (t == 1023) offs[NN] = part[1023];
}

__global__ void fill3(const int* __restrict__ s0, const int* __restrict__ d0,
                      const int* __restrict__ s1, const int* __restrict__ d1,
                      const int* __restrict__ s2, const int* __restrict__ d2,
                      int* __restrict__ cursor_all, int* __restrict__ csrc_all,
                      int* __restrict__ ceid0) {
  const int rel = blockIdx.y;
  const int* src = rel == 0 ? s0 : (rel == 1 ? s1 : s2);
  const int* dst = rel == 0 ? d0 : (rel == 1 ? d1 : d2);
  int* cursor = cursor_all + rel * (NN + 1);
  int* csrc = csrc_all + (size_t)rel * NE;
  for (int e = blockIdx.x * blockDim.x + threadIdx.x; e < NE; e += gridDim.x * blockDim.x) {
    const int p = atomicAdd(&cursor[dst[e]], 1);
    csrc[p] = src[e];
    if (rel == 0) ceid0[p] = e;
  }
}

// ------------- softmax-gather core (one wave, one node, one relation) -------------
__device__ __forceinline__ void gat_one(const int* __restrict__ offs,
                                        const int* __restrict__ csrc,
                                        const int* __restrict__ ceid,
                                        const float* __restrict__ ebias,
                                        const float* __restrict__ s0v,
                                        const float* __restrict__ s1v, float dn,
                                        const __half* __restrict__ hpr, int node,
                                        float* exbuf, int* srcbuf, int lane,
                                        float& o0, float& o1) {
  const int beg = offs[node];
  int cnt = offs[node + 1] - beg;
  if (cnt > CAP) cnt = CAP;
  if (cnt == 0) return;
  __threadfence_block();
  float m = -1e30f;
  for (int i = lane; i < cnt; i += 64) {
    const int sn = csrc[beg + i];
    float logit = s0v[sn] + s1v[sn] + dn;
    if (ebias) logit += ebias[ceid[beg + i]];
    const float e = logit >= 0.f ? logit : 0.2f * logit;
    exbuf[i] = e;
    srcbuf[i] = sn;
    m = fmaxf(m, e);
  }
#pragma unroll
  for (int o = 32; o; o >>= 1) m = fmaxf(m, __shfl_xor(m, o));
  float ssum = 0.f;
  for (int i = lane; i < cnt; i += 64) {
    const float ex = __expf(exbuf[i] - m);
    exbuf[i] = ex;
    ssum += ex;
  }
#pragma unroll
  for (int o = 32; o; o >>= 1) ssum += __shfl_xor(ssum, o);
  const float inv = 1.f / (ssum + 1e-16f);
  __threadfence_block();
  const int c = lane << 1;
  float n0 = 0.f, n1 = 0.f;
  int i = 0;
  for (; i + 2 <= cnt; i += 2) {
    const float w0 = exbuf[i], w1 = exbuf[i + 1];
    const float2 v0 = __half22float2(*(const __half2*)(hpr + (size_t)srcbuf[i] * DDIM + c));
    const float2 v1 = __half22float2(*(const __half2*)(hpr + (size_t)srcbuf[i + 1] * DDIM + c));
    n0 += w0 * v0.x + w1 * v1.x;
    n1 += w0 * v0.y + w1 * v1.y;
  }
  for (; i < cnt; ++i) {
    const float w = exbuf[i];
    const float2 v = __half22float2(*(const __half2*)(hpr + (size_t)srcbuf[i] * DDIM + c));
    n0 += w * v.x;
    n1 += w * v.y;
  }
  const float v0 = n0 * inv, v1 = n1 * inv;
  o0 += (v0 > 0.f ? v0 : expm1f(v0));
  o1 += (v1 > 0.f ? v1 : expm1f(v1));
}

// ------------- fused aggregation: all 40000 nodes in one launch -------------
__global__ __launch_bounds__(256)
void agg_all(const int* __restrict__ offs_all, const int* __restrict__ csrc_all,
             const int* __restrict__ ceid0, const float* __restrict__ ebias,
             const float* __restrict__ s_half, const float* __restrict__ d_half,
             const __half* __restrict__ hp16, float* __restrict__ outf,
             short* __restrict__ ohh, short* __restrict__ ohl, int write_f32) {
  __shared__ float exbuf[4][CAP];
  __shared__ int   srcbuf[4][CAP];
  const int wave = threadIdx.x >> 6, lane = threadIdx.x & 63;
  const int node = blockIdx.x * 4 + wave;
  float o0 = 0.f, o1 = 0.f;
  if (node < NDRUG) {
    const float dn = d_half[node] + d_half[(size_t)3 * NN + node];
    gat_one(offs_all, csrc_all, ceid0, ebias, s_half, s_half + (size_t)3 * NN, dn,
            hp16, node, exbuf[wave], srcbuf[wave], lane, o0, o1);
  } else {
#pragma unroll
    for (int rel = 1; rel <= 2; ++rel) {
      const float dn = d_half[(size_t)rel * NN + node] + d_half[(size_t)(3 + rel) * NN + node];
      gat_one(offs_all + rel * (NN + 1), csrc_all + (size_t)rel * NE, nullptr, nullptr,
              s_half + (size_t)rel * NN, s_half + (size_t)(3 + rel) * NN, dn,
              hp16 + (size_t)rel * NN * DDIM, node, exbuf[wave], srcbuf[wave], lane, o0, o1);
    }
  }
  o0 *= (1.f / 3.f);
  o1 *= (1.f / 3.f);
  const int c = lane << 1;
  if (write_f32) {
    *(float2*)(outf + (size_t)node * DDIM + c) = make_float2(o0, o1);
  } else {
    short h0, l0, h1, l1;
    split1(o0, h0, l0);
    split1(o1, h1, l1);
    *(short2*)(ohh + (size_t)node * DDIM + c) = make_short2(h0, h1);
    *(short2*)(ohl + (size_t)node * DDIM + c) = make_short2(l0, l1);
  }
}

extern "C" void kernel_launch(void* const* d_in, const int* in_sizes, int n_in,
                              void* d_out, int out_size, void* d_ws, size_t ws_size,
                              hipStream_t stream) {
  const float* x_drug    = (const float*)d_in[0];
  const float* x_target  = (const float*)d_in[1];
  const float* W_drug    = (const float*)d_in[2];
  const float* b_drug    = (const float*)d_in[3];
  const float* W_target  = (const float*)d_in[4];
  const float* b_target  = (const float*)d_in[5];
  const float* W_gat     = (const float*)d_in[6];
  const float* a_src     = (const float*)d_in[7];
  const float* a_dst     = (const float*)d_in[8];
  const float* a_edge    = (const float*)d_in[9];
  const float* edge_attr = (const float*)d_in[10];
  const int*   e_dd      = (const int*)d_in[11];
  const int*   e_dt      = (const int*)d_in[12];
  const int*   e_tt      = (const int*)d_in[13];
  float* out = (float*)d_out;

  char* ws = (char*)d_ws;
  size_t off = 0;
  auto alloc = [&](size_t b) -> void* {
    void* p = ws + off;
    off += (b + 255) & ~(size_t)255;
    return p;
  };
  __half* hp16  = (__half*)alloc((size_t)3 * NN * DDIM * 2);
  short* hhA    = (short*)alloc((size_t)NN * DDIM * 2);
  short* hlA    = (short*)alloc((size_t)NN * DDIM * 2);
  short* hhB    = (short*)alloc((size_t)NN * DDIM * 2);
  short* hlB    = (short*)alloc((size_t)NN * DDIM * 2);
  float* s_half = (float*)alloc((size_t)6 * NN * 4);
  float* d_half = (float*)alloc((size_t)6 * NN * 4);
  float* bias0  = (float*)alloc((size_t)NE * 4);
  float* bias1  = (float*)alloc((size_t)NE * 4);
  int* counts   = (int*)alloc((size_t)3 * NN * 4);
  int* offs_all = (int*)alloc((size_t)3 * (NN + 1) * 4);
  int* cur_all  = (int*)alloc((size_t)3 * (NN + 1) * 4);
  int* csrc_all = (int*)alloc((size_t)3 * NE * 4);
  int* ceid0    = (int*)alloc((size_t)NE * 4);
  short* wtd_hi = (short*)alloc((size_t)2048 * 128 * 2);
  short* wtd_lo = (short*)alloc((size_t)2048 * 128 * 2);
  short* wtt_hi = (short*)alloc((size_t)1280 * 128 * 2);
  short* wtt_lo = (short*)alloc((size_t)1280 * 128 * 2);
  short* wtg_hi = (short*)alloc((size_t)6 * 128 * 128 * 2);
  short* wtg_lo = (short*)alloc((size_t)6 * 128 * 128 * 2);

  // 0) weight prep (transpose + hi/lo split)
  prep_w<<<dim3((2048 * 128 + 255) / 256, 1), 256, 0, stream>>>(W_drug, wtd_hi, wtd_lo, 2048);
  prep_w<<<dim3((1280 * 128 + 255) / 256, 1), 256, 0, stream>>>(W_target, wtt_hi, wtt_lo, 1280);
  prep_w<<<dim3((128 * 128 + 255) / 256, 6), 256, 0, stream>>>(W_gat, wtg_hi, wtg_lo, 128);

  // 1) projections -> h hi/lo planes (LDS-free, reg double-buffer)
  gemm_proj<<<1252, 256, 0, stream>>>(x_drug, wtd_hi, wtd_lo, b_drug,
                                      x_target, wtt_hi, wtt_lo, b_target, hhA, hlA);

  // 2) edge biases for both layers (one 256MB pass)
  edge_bias_kernel<<<NE / 4, 256, 0, stream>>>(edge_attr, a_edge, a_edge + DDIM,
                                               bias0, bias1);
  // 3) CSR build (3 relations, reused by both layers)
  hipMemsetAsync(counts, 0, (size_t)3 * NN * 4, stream);
  count3<<<dim3(170, 3), 256, 0, stream>>>(e_dd + NE, e_dt + NE, e_tt + NE, counts);
  scan3<<<3, 1024, 0, stream>>>(counts, offs_all, cur_all);
  fill3<<<dim3(170, 3), 256, 0, stream>>>(e_dd, e_dd + NE, e_dt, e_dt + NE,
                                          e_tt, e_tt + NE, cur_all, csrc_all, ceid0);

  // 4) two GAT layers
  // layer 0
  gemm_gat<<<dim3(1250, 3), 256, 0, stream>>>(hhA, hlA, wtg_hi, wtg_lo,
                                              a_src, a_dst, hp16, s_half, d_half);
  agg_all<<<NN / 4, 256, 0, stream>>>(offs_all, csrc_all, ceid0, bias0,
                                      s_half, d_half, hp16, nullptr, hhB, hlB, 0);
  // layer 1
  gemm_gat<<<dim3(1250, 3), 256, 0, stream>>>(hhB, hlB,
                                              wtg_hi + (size_t)3 * DDIM * DDIM,
                                              wtg_lo + (size_t)3 * DDIM * DDIM,
                                              a_src + 3 * DDIM, a_dst + 3 * DDIM,
                                              hp16, s_half, d_half);
  agg_all<<<NN / 4, 256, 0, stream>>>(offs_all, csrc_all, ceid0, bias1,
                                      s_half, d_half, hp16, out, nullptr, nullptr, 1);
}

// Round 8
// 742.221 us; speedup vs baseline: 1.3651x; 1.3651x over previous
//
#include <hip/hip_runtime.h>
#include <hip/hip_fp16.h>

#define NDRUG 20000
#define NTGT  20000
#define NN    40000
#define NE    500000
#define DDIM  128
#define CAP   96
#define AS1 __attribute__((address_space(1)))
#define AS3 __attribute__((address_space(3)))

typedef __attribute__((ext_vector_type(4))) float f32x4;
typedef __attribute__((ext_vector_type(8))) short s16x8;

__device__ inline unsigned short bf_rn(float x) {
  unsigned u = __float_as_uint(x);
  return (unsigned short)((u + 0x7FFFu + ((u >> 16) & 1u)) >> 16);
}
// fp32 -> bf16 hi (RTN) + lo (RTN residual)
__device__ __forceinline__ void split1(float x, short& h, short& l) {
  const unsigned u = __float_as_uint(x);
  const unsigned hu = (u + 0x7FFFu + ((u >> 16) & 1u)) & 0xFFFF0000u;
  h = (short)(hu >> 16);
  l = (short)bf_rn(x - __uint_as_float(hu));
}
__device__ __forceinline__ void cvt8(const float4 a, const float4 b, s16x8& h, s16x8& l) {
  const float xs[8] = {a.x, a.y, a.z, a.w, b.x, b.y, b.z, b.w};
#pragma unroll
  for (int j = 0; j < 8; ++j) {
    short hh, ll;
    split1(xs[j], hh, ll);
    h[j] = hh; l[j] = ll;
  }
}
__device__ __forceinline__ void glds16(const void* g, void* l) {
  __builtin_amdgcn_global_load_lds((const AS1 unsigned*)g, (AS3 unsigned*)l, 16, 0, 0);
}
__device__ __forceinline__ f32x4 mfma(const s16x8& a, const s16x8& b, const f32x4& c) {
  return __builtin_amdgcn_mfma_f32_16x16x32_bf16(a, b, c, 0, 0, 0);
}

// ------- weight prep: W [K][128] fp32 -> packed fragment tiles, hi/lo bf16 -------
// Packed layout: [K/32 tiles][512 chunks][8 shorts]; chunk = col*4 + kg holds
// W[kt*32 + kg*8 + j][col]. ds_read of chunk col*4+kg is bank-group-uniform.
__global__ void prep_pack(const float* __restrict__ W, short* __restrict__ ph,
                          short* __restrict__ pl, int K) {
  const size_t mat = (size_t)blockIdx.y * K * 128;
  const int idx = blockIdx.x * blockDim.x + threadIdx.x;
  if (idx >= K * 128) return;
  const int kt = idx >> 12, r = idx & 4095;
  const int chunk = r >> 3, j = r & 7;
  const int col = chunk >> 2, kg = chunk & 3;
  const int k = kt * 32 + kg * 8 + j;
  short h, l;
  split1(W[mat + (size_t)k * 128 + col], h, l);
  ph[mat + idx] = h;
  pl[mat + idx] = l;
}

// ---------------- 2-phase glds projection GEMM ----------------
// BM=128 BN=128 BK=32, 256 threads, waves 2x2 (each 64x64).
// A fp32 staged via glds with (row&7)-XOR-swizzled SOURCE chunks (linear dest);
// converted to bf16 hi/lo at ds_read. B pre-packed fragment layout, linear glds.
// One barrier per K-step; next tile's loads fly under current tile's MFMA.
__global__ __launch_bounds__(256)
void gemm_proj(const float* __restrict__ xd, const short* __restrict__ pdh,
               const short* __restrict__ pdl, const float* __restrict__ bd,
               const float* __restrict__ xt, const short* __restrict__ pth,
               const short* __restrict__ ptl, const float* __restrict__ bt,
               short* __restrict__ hh, short* __restrict__ hl) {
  __shared__ float Af[2][128 * 32];          // 16KB x2
  __shared__ short Bf[2][2][512 * 8];        // [buf][plane] 8KB each -> 32KB

  int b = blockIdx.x;
  const float* A; const short* BH; const short* BL; const float* bias;
  int M, K, rowbase;
  if (b < 157) { A = xd; BH = pdh; BL = pdl; bias = bd; M = NDRUG; K = 2048; rowbase = 0; }
  else { b -= 157; A = xt; BH = pth; BL = ptl; bias = bt; M = NTGT; K = 1280; rowbase = NDRUG; }
  const int bm = b * 128;

  const int t = threadIdx.x, w = t >> 6, lane = t & 63;
  const int wm = w >> 1, wn = w & 1;
  const int lr = lane & 15, kg = lane >> 4;
  const int steps = K >> 5;

  f32x4 acc[4][4] = {};

  auto stage = [&](int buf, int kt) {
    const int kk = kt << 5;
    // A: 1024 chunks of 16B, source-chunk swizzled by row&7
#pragma unroll
    for (int call = 0; call < 4; ++call) {
      const int d = call * 256 + t;
      const int row = d >> 3, cpos = d & 7;
      const int csrc = cpos ^ (row & 7);
      int grow = bm + row; if (grow >= M) grow = M - 1;
      glds16(A + (size_t)grow * K + kk + csrc * 4, &Af[buf][(size_t)(call * 256 + (w << 6)) * 4]);
    }
    // B: pure linear copy of packed tile
#pragma unroll
    for (int pl = 0; pl < 2; ++pl) {
      const short* src = pl ? BL : BH;
#pragma unroll
      for (int call = 0; call < 2; ++call) {
        const int d = call * 256 + t;
        glds16(src + (size_t)kt * 4096 + d * 8, &Bf[buf][pl][(size_t)(call * 256 + (w << 6)) * 8]);
      }
    }
  };

  auto compute = [&](int buf) {
    s16x8 ah[4], al[4];
#pragma unroll
    for (int mi = 0; mi < 4; ++mi) {
      const int row = wm * 64 + mi * 16 + lr;
      const int c0 = (kg * 2) ^ (row & 7);
      const int c1 = (kg * 2 + 1) ^ (row & 7);
      const float4 va = *(const float4*)&Af[buf][row * 32 + c0 * 4];
      const float4 vb = *(const float4*)&Af[buf][row * 32 + c1 * 4];
      cvt8(va, vb, ah[mi], al[mi]);
    }
#pragma unroll
    for (int n = 0; n < 4; ++n) {
      const int col = wn * 64 + n * 16 + lr;
      const s16x8 bh = *(const s16x8*)&Bf[buf][0][(col * 4 + kg) * 8];
      const s16x8 bl = *(const s16x8*)&Bf[buf][1][(col * 4 + kg) * 8];
#pragma unroll
      for (int mi = 0; mi < 4; ++mi) {
        acc[mi][n] = mfma(ah[mi], bh, acc[mi][n]);
        acc[mi][n] = mfma(ah[mi], bl, acc[mi][n]);
        acc[mi][n] = mfma(al[mi], bh, acc[mi][n]);
      }
    }
  };

  stage(0, 0);
  __syncthreads();
  int cur = 0;
  for (int kt = 0; kt < steps - 1; ++kt) {
    stage(cur ^ 1, kt + 1);
    compute(cur);
    __syncthreads();
    cur ^= 1;
  }
  compute(cur);

#pragma unroll
  for (int n = 0; n < 4; ++n) {
    const int col = wn * 64 + n * 16 + lr;
    const float bv = bias[col];
#pragma unroll
    for (int mi = 0; mi < 4; ++mi) {
#pragma unroll
      for (int r = 0; r < 4; ++r) {
        const int row = bm + wm * 64 + mi * 16 + kg * 4 + r;
        if (row < M) {
          short h, l;
          split1(acc[mi][n][r] + bv, h, l);
          hh[(size_t)(rowbase + row) * DDIM + col] = h;
          hl[(size_t)(rowbase + row) * DDIM + col] = l;
        }
      }
    }
  }
}

// ---------------- 2-phase glds GAT GEMM + fused s/d ----------------
// A = h bf16 hi/lo planes [NN][128]; grid (313, 3); K=128 (4 steps).
__global__ __launch_bounds__(256)
void gemm_gat(const short* __restrict__ ahh, const short* __restrict__ ahl,
              const short* __restrict__ PH3, const short* __restrict__ PL3,
              const float* __restrict__ asrc3, const float* __restrict__ adst3,
              __half* __restrict__ hp16, float* __restrict__ s_all,
              float* __restrict__ d_all) {
  __shared__ short Apl[2][2][512 * 8];   // [buf][plane] 8KB each
  __shared__ short Bf[2][2][512 * 8];
  __shared__ float sred[2][128], dred[2][128];

  const int rel = blockIdx.y;
  const int bm = blockIdx.x * 128;
  const short* BH = PH3 + (size_t)rel * DDIM * DDIM;
  const short* BL = PL3 + (size_t)rel * DDIM * DDIM;

  const int t = threadIdx.x, w = t >> 6, lane = t & 63;
  const int wm = w >> 1, wn = w & 1;
  const int lr = lane & 15, kg = lane >> 4;

  f32x4 acc[4][4] = {};

  auto stage = [&](int buf, int kt) {
#pragma unroll
    for (int pl = 0; pl < 2; ++pl) {
      const short* src = pl ? ahl : ahh;
#pragma unroll
      for (int call = 0; call < 2; ++call) {
        const int d = call * 256 + t;            // 0..511
        const int row = d >> 2, cpos = d & 3;
        int grow = bm + row; if (grow >= NN) grow = NN - 1;
        glds16(src + (size_t)grow * DDIM + kt * 32 + cpos * 8,
               &Apl[buf][pl][(size_t)(call * 256 + (w << 6)) * 8]);
      }
    }
#pragma unroll
    for (int pl = 0; pl < 2; ++pl) {
      const short* src = pl ? BL : BH;
#pragma unroll
      for (int call = 0; call < 2; ++call) {
        const int d = call * 256 + t;
        glds16(src + (size_t)kt * 4096 + d * 8, &Bf[buf][pl][(size_t)(call * 256 + (w << 6)) * 8]);
      }
    }
  };

  auto compute = [&](int buf) {
    s16x8 ah[4], al[4];
#pragma unroll
    for (int mi = 0; mi < 4; ++mi) {
      const int row = wm * 64 + mi * 16 + lr;
      ah[mi] = *(const s16x8*)&Apl[buf][0][(row * 4 + kg) * 8];
      al[mi] = *(const s16x8*)&Apl[buf][1][(row * 4 + kg) * 8];
    }
#pragma unroll
    for (int n = 0; n < 4; ++n) {
      const int col = wn * 64 + n * 16 + lr;
      const s16x8 bh = *(const s16x8*)&Bf[buf][0][(col * 4 + kg) * 8];
      const s16x8 bl = *(const s16x8*)&Bf[buf][1][(col * 4 + kg) * 8];
#pragma unroll
      for (int mi = 0; mi < 4; ++mi) {
        acc[mi][n] = mfma(ah[mi], bh, acc[mi][n]);
        acc[mi][n] = mfma(ah[mi], bl, acc[mi][n]);
        acc[mi][n] = mfma(al[mi], bh, acc[mi][n]);
      }
    }
  };

  stage(0, 0);
  __syncthreads();
  int cur = 0;
  for (int kt = 0; kt < 3; ++kt) {
    stage(cur ^ 1, kt + 1);
    compute(cur);
    __syncthreads();
    cur ^= 1;
  }
  compute(cur);

  // hp fp16 write + s/d partials
  __half* hpr = hp16 + (size_t)rel * NN * DDIM;
  float asv[4], adv[4];
#pragma unroll
  for (int n = 0; n < 4; ++n) {
    asv[n] = asrc3[rel * DDIM + wn * 64 + n * 16 + lr];
    adv[n] = adst3[rel * DDIM + wn * 64 + n * 16 + lr];
  }
#pragma unroll
  for (int mi = 0; mi < 4; ++mi) {
#pragma unroll
    for (int r = 0; r < 4; ++r) {
      const int rloc = wm * 64 + mi * 16 + kg * 4 + r;
      const int grow = bm + rloc;
      float ps = 0.f, pd = 0.f;
#pragma unroll
      for (int n = 0; n < 4; ++n) {
        const int col = wn * 64 + n * 16 + lr;
        if (grow < NN) hpr[(size_t)grow * DDIM + col] = __float2half_rn(acc[mi][n][r]);
        ps += acc[mi][n][r] * asv[n];
        pd += acc[mi][n][r] * adv[n];
      }
#pragma unroll
      for (int o = 1; o < 16; o <<= 1) { ps += __shfl_xor(ps, o); pd += __shfl_xor(pd, o); }
      if (lr == 0) { sred[wn][rloc] = ps; dred[wn][rloc] = pd; }
    }
  }
  __syncthreads();
  if (t < 128 && bm + t < NN) {
    s_all[(size_t)rel * NN + bm + t] = sred[0][t] + sred[1][t];
    d_all[(size_t)rel * NN + bm + t] = dred[0][t] + dred[1][t];
  }
}

// ------------- edge bias for BOTH layers, float2 loads -------------
__global__ __launch_bounds__(256)
void edge_bias_kernel(const float* __restrict__ ea, const float* __restrict__ ae0,
                      const float* __restrict__ ae1, float* __restrict__ b0,
                      float* __restrict__ b1) {
  const int wave = threadIdx.x >> 6, lane = threadIdx.x & 63;
  const int e = blockIdx.x * 4 + wave;
  if (e >= NE) return;
  const float2 v = *(const float2*)(ea + (size_t)e * DDIM + (lane << 1));
  float s0 = v.x * ae0[lane << 1] + v.y * ae0[(lane << 1) + 1];
  float s1 = v.x * ae1[lane << 1] + v.y * ae1[(lane << 1) + 1];
#pragma unroll
  for (int o = 32; o; o >>= 1) { s0 += __shfl_xor(s0, o); s1 += __shfl_xor(s1, o); }
  if (lane == 0) { b0[e] = s0; b1[e] = s1; }
}

// ------------- CSR build (3 relations batched) -------------
__global__ void count3(const int* __restrict__ d0, const int* __restrict__ d1,
                       const int* __restrict__ d2, int* __restrict__ counts) {
  const int rel = blockIdx.y;
  const int* dst = rel == 0 ? d0 : (rel == 1 ? d1 : d2);
  int* c = counts + rel * NN;
  for (int e = blockIdx.x * blockDim.x + threadIdx.x; e < NE; e += gridDim.x * blockDim.x)
    atomicAdd(&c[dst[e]], 1);
}

__global__ __launch_bounds__(1024)
void scan3(const int* __restrict__ counts_all, int* __restrict__ offs_all,
           int* __restrict__ cursor_all) {
  const int rel = blockIdx.x;
  const int* counts = counts_all + rel * NN;
  int* offs = offs_all + rel * (NN + 1);
  int* cursor = cursor_all + rel * (NN + 1);
  __shared__ int part[1024];
  const int t = threadIdx.x;
  const int CH = 40;
  const int base = t * CH;
  const int lim = min(base + CH, NN);
  int sum = 0;
  for (int i = base; i < lim; ++i) sum += counts[i];
  part[t] = sum;
  __syncthreads();
  for (int o = 1; o < 1024; o <<= 1) {
    const int v = (t >= o) ? part[t - o] : 0;
    __syncthreads();
    part[t] += v;
    __syncthreads();
  }
  int run = (t == 0) ? 0 : part[t - 1];
  for (int i = base; i < lim; ++i) { offs[i] = run; cursor[i] = run; run += counts[i]; }
  if (t == 1023) offs[NN] = part[1023];
}

__global__ void fill3(const int* __restrict__ s0, const int* __restrict__ d0,
                      const int* __restrict__ s1, const int* __restrict__ d1,
                      const int* __restrict__ s2, const int* __restrict__ d2,
                      int* __restrict__ cursor_all, int* __restrict__ csrc_all,
                      int* __restrict__ ceid0) {
  const int rel = blockIdx.y;
  const int* src = rel == 0 ? s0 : (rel == 1 ? s1 : s2);
  const int* dst = rel == 0 ? d0 : (rel == 1 ? d1 : d2);
  int* cursor = cursor_all + rel * (NN + 1);
  int* csrc = csrc_all + (size_t)rel * NE;
  for (int e = blockIdx.x * blockDim.x + threadIdx.x; e < NE; e += gridDim.x * blockDim.x) {
    const int p = atomicAdd(&cursor[dst[e]], 1);
    csrc[p] = src[e];
    if (rel == 0) ceid0[p] = e;
  }
}

// ------------- softmax-gather core (one wave, one node, one relation) -------------
__device__ __forceinline__ void gat_one(const int* __restrict__ offs,
                                        const int* __restrict__ csrc,
                                        const int* __restrict__ ceid,
                                        const float* __restrict__ ebias,
                                        const float* __restrict__ s, float dn,
                                        const __half* __restrict__ hpr, int node,
                                        float* exbuf, int* srcbuf, int lane,
                                        float& o0, float& o1) {
  const int beg = offs[node];
  int cnt = offs[node + 1] - beg;
  if (cnt > CAP) cnt = CAP;
  if (cnt == 0) return;
  __threadfence_block();
  float m = -1e30f;
  for (int i = lane; i < cnt; i += 64) {
    const int sn = csrc[beg + i];
    float logit = s[sn] + dn;
    if (ebias) logit += ebias[ceid[beg + i]];
    const float e = logit >= 0.f ? logit : 0.2f * logit;
    exbuf[i] = e;
    srcbuf[i] = sn;
    m = fmaxf(m, e);
  }
#pragma unroll
  for (int o = 32; o; o >>= 1) m = fmaxf(m, __shfl_xor(m, o));
  float ssum = 0.f;
  for (int i = lane; i < cnt; i += 64) {
    const float ex = __expf(exbuf[i] - m);
    exbuf[i] = ex;
    ssum += ex;
  }
#pragma unroll
  for (int o = 32; o; o >>= 1) ssum += __shfl_xor(ssum, o);
  const float inv = 1.f / (ssum + 1e-16f);
  __threadfence_block();
  const int c = lane << 1;
  float n0 = 0.f, n1 = 0.f;
  int i = 0;
  for (; i + 2 <= cnt; i += 2) {
    const float w0 = exbuf[i], w1 = exbuf[i + 1];
    const float2 v0 = __half22float2(*(const __half2*)(hpr + (size_t)srcbuf[i] * DDIM + c));
    const float2 v1 = __half22float2(*(const __half2*)(hpr + (size_t)srcbuf[i + 1] * DDIM + c));
    n0 += w0 * v0.x + w1 * v1.x;
    n1 += w0 * v0.y + w1 * v1.y;
  }
  for (; i < cnt; ++i) {
    const float w = exbuf[i];
    const float2 v = __half22float2(*(const __half2*)(hpr + (size_t)srcbuf[i] * DDIM + c));
    n0 += w * v.x;
    n1 += w * v.y;
  }
  const float v0 = n0 * inv, v1 = n1 * inv;
  o0 += (v0 > 0.f ? v0 : expm1f(v0));
  o1 += (v1 > 0.f ? v1 : expm1f(v1));
}

// ------------- fused aggregation: all 40000 nodes in one launch -------------
__global__ __launch_bounds__(256)
void agg_all(const int* __restrict__ offs_all, const int* __restrict__ csrc_all,
             const int* __restrict__ ceid0, const float* __restrict__ ebias,
             const float* __restrict__ s_all, const float* __restrict__ d_all,
             const __half* __restrict__ hp16, float* __restrict__ outf,
             short* __restrict__ ohh, short* __restrict__ ohl, int write_f32) {
  __shared__ float exbuf[4][CAP];
  __shared__ int   srcbuf[4][CAP];
  const int wave = threadIdx.x >> 6, lane = threadIdx.x & 63;
  const int node = blockIdx.x * 4 + wave;
  float o0 = 0.f, o1 = 0.f;
  if (node < NDRUG) {
    gat_one(offs_all, csrc_all, ceid0, ebias, s_all, d_all[node],
            hp16, node, exbuf[wave], srcbuf[wave], lane, o0, o1);
  } else {
#pragma unroll
    for (int rel = 1; rel <= 2; ++rel) {
      gat_one(offs_all + rel * (NN + 1), csrc_all + (size_t)rel * NE, nullptr, nullptr,
              s_all + (size_t)rel * NN, d_all[(size_t)rel * NN + node],
              hp16 + (size_t)rel * NN * DDIM, node, exbuf[wave], srcbuf[wave], lane, o0, o1);
    }
  }
  o0 *= (1.f / 3.f);
  o1 *= (1.f / 3.f);
  const int c = lane << 1;
  if (write_f32) {
    *(float2*)(outf + (size_t)node * DDIM + c) = make_float2(o0, o1);
  } else {
    short h0, l0, h1, l1;
    split1(o0, h0, l0);
    split1(o1, h1, l1);
    *(short2*)(ohh + (size_t)node * DDIM + c) = make_short2(h0, h1);
    *(short2*)(ohl + (size_t)node * DDIM + c) = make_short2(l0, l1);
  }
}

extern "C" void kernel_launch(void* const* d_in, const int* in_sizes, int n_in,
                              void* d_out, int out_size, void* d_ws, size_t ws_size,
                              hipStream_t stream) {
  const float* x_drug    = (const float*)d_in[0];
  const float* x_target  = (const float*)d_in[1];
  const float* W_drug    = (const float*)d_in[2];
  const float* b_drug    = (const float*)d_in[3];
  const float* W_target  = (const float*)d_in[4];
  const float* b_target  = (const float*)d_in[5];
  const float* W_gat     = (const float*)d_in[6];
  const float* a_src     = (const float*)d_in[7];
  const float* a_dst     = (const float*)d_in[8];
  const float* a_edge    = (const float*)d_in[9];
  const float* edge_attr = (const float*)d_in[10];
  const int*   e_dd      = (const int*)d_in[11];
  const int*   e_dt      = (const int*)d_in[12];
  const int*   e_tt      = (const int*)d_in[13];
  float* out = (float*)d_out;

  char* ws = (char*)d_ws;
  size_t off = 0;
  auto alloc = [&](size_t b) -> void* {
    void* p = ws + off;
    off += (b + 255) & ~(size_t)255;
    return p;
  };
  __half* hp16  = (__half*)alloc((size_t)3 * NN * DDIM * 2);
  short* hhA    = (short*)alloc((size_t)NN * DDIM * 2);
  short* hlA    = (short*)alloc((size_t)NN * DDIM * 2);
  short* hhB    = (short*)alloc((size_t)NN * DDIM * 2);
  short* hlB    = (short*)alloc((size_t)NN * DDIM * 2);
  float* s_all  = (float*)alloc((size_t)3 * NN * 4);
  float* d_allb = (float*)alloc((size_t)3 * NN * 4);
  float* bias0  = (float*)alloc((size_t)NE * 4);
  float* bias1  = (float*)alloc((size_t)NE * 4);
  int* counts   = (int*)alloc((size_t)3 * NN * 4);
  int* offs_all = (int*)alloc((size_t)3 * (NN + 1) * 4);
  int* cur_all  = (int*)alloc((size_t)3 * (NN + 1) * 4);
  int* csrc_all = (int*)alloc((size_t)3 * NE * 4);
  int* ceid0    = (int*)alloc((size_t)NE * 4);
  short* pwd_h  = (short*)alloc((size_t)2048 * 128 * 2);
  short* pwd_l  = (short*)alloc((size_t)2048 * 128 * 2);
  short* pwt_h  = (short*)alloc((size_t)1280 * 128 * 2);
  short* pwt_l  = (short*)alloc((size_t)1280 * 128 * 2);
  short* pwg_h  = (short*)alloc((size_t)6 * 128 * 128 * 2);
  short* pwg_l  = (short*)alloc((size_t)6 * 128 * 128 * 2);

  // 0) weight prep: packed fragment tiles, hi/lo split
  prep_pack<<<dim3(1024, 1), 256, 0, stream>>>(W_drug, pwd_h, pwd_l, 2048);
  prep_pack<<<dim3(640, 1), 256, 0, stream>>>(W_target, pwt_h, pwt_l, 1280);
  prep_pack<<<dim3(64, 6), 256, 0, stream>>>(W_gat, pwg_h, pwg_l, 128);

  // 1) projections -> h hi/lo planes (2-phase glds pipeline)
  gemm_proj<<<314, 256, 0, stream>>>(x_drug, pwd_h, pwd_l, b_drug,
                                     x_target, pwt_h, pwt_l, b_target, hhA, hlA);

  // 2) edge biases for both layers (one 256MB pass)
  edge_bias_kernel<<<NE / 4, 256, 0, stream>>>(edge_attr, a_edge, a_edge + DDIM,
                                               bias0, bias1);
  // 3) CSR build (3 relations, reused by both layers)
  hipMemsetAsync(counts, 0, (size_t)3 * NN * 4, stream);
  count3<<<dim3(170, 3), 256, 0, stream>>>(e_dd + NE, e_dt + NE, e_tt + NE, counts);
  scan3<<<3, 1024, 0, stream>>>(counts, offs_all, cur_all);
  fill3<<<dim3(170, 3), 256, 0, stream>>>(e_dd, e_dd + NE, e_dt, e_dt + NE,
                                          e_tt, e_tt + NE, cur_all, csrc_all, ceid0);

  // 4) two GAT layers
  // layer 0
  gemm_gat<<<dim3(313, 3), 256, 0, stream>>>(hhA, hlA, pwg_h, pwg_l,
                                             a_src, a_dst, hp16, s_all, d_allb);
  agg_all<<<NN / 4, 256, 0, stream>>>(offs_all, csrc_all, ceid0, bias0,
                                      s_all, d_allb, hp16, nullptr, hhB, hlB, 0);
  // layer 1
  gemm_gat<<<dim3(313, 3), 256, 0, stream>>>(hhB, hlB,
                                             pwg_h + (size_t)3 * DDIM * DDIM,
                                             pwg_l + (size_t)3 * DDIM * DDIM,
                                             a_src + 3 * DDIM, a_dst + 3 * DDIM,
                                             hp16, s_all, d_allb);
  agg_all<<<NN / 4, 256, 0, stream>>>(offs_all, csrc_all, ceid0, bias1,
                                      s_all, d_allb, hp16, out, nullptr, nullptr, 1);
}

// Round 9
// 724.730 us; speedup vs baseline: 1.3981x; 1.0241x over previous
//
#include <hip/hip_runtime.h>
#include <hip/hip_fp16.h>

#define NDRUG 20000
#define NTGT  20000
#define NN    40000
#define NE    500000
#define DDIM  128
#define CAP   96
#define AS1 __attribute__((address_space(1)))
#define AS3 __attribute__((address_space(3)))

typedef __attribute__((ext_vector_type(4))) float f32x4;
typedef __attribute__((ext_vector_type(8))) short s16x8;

__device__ inline unsigned short bf_rn(float x) {
  unsigned u = __float_as_uint(x);
  return (unsigned short)((u + 0x7FFFu + ((u >> 16) & 1u)) >> 16);
}
// fp32 -> bf16 hi (RTN) + lo (RTN residual)
__device__ __forceinline__ void split1(float x, short& h, short& l) {
  const unsigned u = __float_as_uint(x);
  const unsigned hu = (u + 0x7FFFu + ((u >> 16) & 1u)) & 0xFFFF0000u;
  h = (short)(hu >> 16);
  l = (short)bf_rn(x - __uint_as_float(hu));
}
__device__ __forceinline__ void cvt8(const float4 a, const float4 b, s16x8& h, s16x8& l) {
  const float xs[8] = {a.x, a.y, a.z, a.w, b.x, b.y, b.z, b.w};
#pragma unroll
  for (int j = 0; j < 8; ++j) {
    short hh, ll;
    split1(xs[j], hh, ll);
    h[j] = hh; l[j] = ll;
  }
}
__device__ __forceinline__ void glds16(const void* g, void* l) {
  __builtin_amdgcn_global_load_lds((const AS1 unsigned*)g, (AS3 unsigned*)l, 16, 0, 0);
}
__device__ __forceinline__ f32x4 mfma(const s16x8& a, const s16x8& b, const f32x4& c) {
  return __builtin_amdgcn_mfma_f32_16x16x32_bf16(a, b, c, 0, 0, 0);
}

// ------- weight prep: W [K][128] fp32 -> packed fragment tiles, hi/lo bf16 -------
// Packed: [K/32 tiles][512 chunks][8 shorts]; chunk col*4+kg holds W[kt*32+kg*8+j][col].
__global__ void prep_pack(const float* __restrict__ W, short* __restrict__ ph,
                          short* __restrict__ pl, int K) {
  const size_t mat = (size_t)blockIdx.y * K * 128;
  const int idx = blockIdx.x * blockDim.x + threadIdx.x;
  if (idx >= K * 128) return;
  const int kt = idx >> 12, r = idx & 4095;
  const int chunk = r >> 3, j = r & 7;
  const int col = chunk >> 2, kg = chunk & 3;
  const int k = kt * 32 + kg * 8 + j;
  short h, l;
  split1(W[mat + (size_t)k * 128 + col], h, l);
  ph[mat + idx] = h;
  pl[mat + idx] = l;
}

// ---------------- 2-phase glds projection GEMM, BM=32 BN=128 BK=32 ----------------
// 40KB LDS -> 4 blocks/CU. Grid 1250 (625 drug + 625 target).
// A fp32 glds with (row&7)-XOR source-chunk swizzle (linear dest); bf16 hi/lo at read.
// B pre-packed fragment tiles, linear glds, L2-resident.
__global__ __launch_bounds__(256)
void gemm_proj(const float* __restrict__ xd, const short* __restrict__ pdh,
               const short* __restrict__ pdl, const float* __restrict__ bd,
               const float* __restrict__ xt, const short* __restrict__ pth,
               const short* __restrict__ ptl, const float* __restrict__ bt,
               short* __restrict__ hh, short* __restrict__ hl) {
  __shared__ float Af[2][32 * 32];      // 4KB x2
  __shared__ short Bf[2][2][4096];      // [buf][plane] 8KB -> 32KB

  int b = blockIdx.x;
  const float* A; const short* BH; const short* BL; const float* bias;
  int K, rowbase;
  if (b < 625) { A = xd; BH = pdh; BL = pdl; bias = bd; K = 2048; rowbase = 0; }
  else { b -= 625; A = xt; BH = pth; BL = ptl; bias = bt; K = 1280; rowbase = NDRUG; }
  const int bm = b * 32;

  const int t = threadIdx.x, w = t >> 6, lane = t & 63;
  const int wm = w >> 1, wn = w & 1;
  const int lr = lane & 15, kg = lane >> 4;
  const int steps = K >> 5;

  f32x4 acc[4] = {};

  auto stage = [&](int buf, int kt) {
    const int kk = kt << 5;
    {
      const int row = t >> 3, cpos = t & 7;
      const int csrc = cpos ^ (row & 7);
      glds16(A + (size_t)(bm + row) * K + kk + csrc * 4, &Af[buf][(w << 6) * 4]);
    }
#pragma unroll
    for (int pl = 0; pl < 2; ++pl) {
      const short* src = pl ? BL : BH;
#pragma unroll
      for (int call = 0; call < 2; ++call) {
        const int d = call * 256 + t;
        glds16(src + (size_t)kt * 4096 + d * 8, &Bf[buf][pl][(call * 256 + (w << 6)) * 8]);
      }
    }
  };

  auto compute = [&](int buf) {
    const int row = wm * 16 + lr, s = lr & 7;
    const float4 va = *(const float4*)&Af[buf][(row * 8 + ((kg * 2) ^ s)) * 4];
    const float4 vb = *(const float4*)&Af[buf][(row * 8 + ((kg * 2 + 1) ^ s)) * 4];
    s16x8 ah, al;
    cvt8(va, vb, ah, al);
#pragma unroll
    for (int n = 0; n < 4; ++n) {
      const int col = wn * 64 + n * 16 + lr;
      const s16x8 bh = *(const s16x8*)&Bf[buf][0][(col * 4 + kg) * 8];
      const s16x8 bl = *(const s16x8*)&Bf[buf][1][(col * 4 + kg) * 8];
      acc[n] = mfma(ah, bh, acc[n]);
      acc[n] = mfma(ah, bl, acc[n]);
      acc[n] = mfma(al, bh, acc[n]);
    }
  };

  stage(0, 0);
  __syncthreads();
  int cur = 0;
  for (int kt = 0; kt < steps - 1; ++kt) {
    stage(cur ^ 1, kt + 1);
    compute(cur);
    __syncthreads();
    cur ^= 1;
  }
  compute(cur);

#pragma unroll
  for (int n = 0; n < 4; ++n) {
    const int col = wn * 64 + n * 16 + lr;
    const float bv = bias[col];
#pragma unroll
    for (int r = 0; r < 4; ++r) {
      const int row = rowbase + bm + wm * 16 + kg * 4 + r;
      short h, l;
      split1(acc[n][r] + bv, h, l);
      hh[(size_t)row * DDIM + col] = h;
      hl[(size_t)row * DDIM + col] = l;
    }
  }
}

// ---------------- 2-phase glds GAT GEMM + fused s/d, BM=32 ----------------
// A = h bf16 hi/lo planes [NN][128]; grid (1250, 3); K=128 (4 steps). 40KB LDS.
__global__ __launch_bounds__(256)
void gemm_gat(const short* __restrict__ ahh, const short* __restrict__ ahl,
              const short* __restrict__ PH3, const short* __restrict__ PL3,
              const float* __restrict__ asrc3, const float* __restrict__ adst3,
              __half* __restrict__ hp16, float* __restrict__ s_all,
              float* __restrict__ d_all) {
  __shared__ short Apl[2][2][1024];     // [buf][plane] 2KB -> 8KB
  __shared__ short Bf[2][2][4096];      // 32KB
  __shared__ float sred[2][32], dred[2][32];

  const int rel = blockIdx.y;
  const int bm = blockIdx.x * 32;
  const short* BH = PH3 + (size_t)rel * DDIM * DDIM;
  const short* BL = PL3 + (size_t)rel * DDIM * DDIM;

  const int t = threadIdx.x, w = t >> 6, lane = t & 63;
  const int wm = w >> 1, wn = w & 1;
  const int lr = lane & 15, kg = lane >> 4;

  f32x4 acc[4] = {};

  auto stage = [&](int buf, int kt) {
    {
      const int pl = t >> 7, i = t & 127;
      const int row = i >> 2, cpos = i & 3;
      const short* src = pl ? ahl : ahh;
      glds16(src + (size_t)(bm + row) * DDIM + kt * 32 + cpos * 8,
             &Apl[buf][w >> 1][(w & 1) * 512]);
    }
#pragma unroll
    for (int pl = 0; pl < 2; ++pl) {
      const short* src = pl ? BL : BH;
#pragma unroll
      for (int call = 0; call < 2; ++call) {
        const int d = call * 256 + t;
        glds16(src + (size_t)kt * 4096 + d * 8, &Bf[buf][pl][(call * 256 + (w << 6)) * 8]);
      }
    }
  };

  auto compute = [&](int buf) {
    const int row = wm * 16 + lr;
    const s16x8 ah = *(const s16x8*)&Apl[buf][0][(row * 4 + kg) * 8];
    const s16x8 al = *(const s16x8*)&Apl[buf][1][(row * 4 + kg) * 8];
#pragma unroll
    for (int n = 0; n < 4; ++n) {
      const int col = wn * 64 + n * 16 + lr;
      const s16x8 bh = *(const s16x8*)&Bf[buf][0][(col * 4 + kg) * 8];
      const s16x8 bl = *(const s16x8*)&Bf[buf][1][(col * 4 + kg) * 8];
      acc[n] = mfma(ah, bh, acc[n]);
      acc[n] = mfma(ah, bl, acc[n]);
      acc[n] = mfma(al, bh, acc[n]);
    }
  };

  stage(0, 0);
  __syncthreads();
  int cur = 0;
  for (int kt = 0; kt < 3; ++kt) {
    stage(cur ^ 1, kt + 1);
    compute(cur);
    __syncthreads();
    cur ^= 1;
  }
  compute(cur);

  // hp fp16 write + fused s/d
  __half* hpr = hp16 + (size_t)rel * NN * DDIM;
  float asv[4], adv[4];
#pragma unroll
  for (int n = 0; n < 4; ++n) {
    asv[n] = asrc3[rel * DDIM + wn * 64 + n * 16 + lr];
    adv[n] = adst3[rel * DDIM + wn * 64 + n * 16 + lr];
  }
#pragma unroll
  for (int r = 0; r < 4; ++r) {
    const int rloc = wm * 16 + kg * 4 + r;
    const int grow = bm + rloc;
    float ps = 0.f, pd = 0.f;
#pragma unroll
    for (int n = 0; n < 4; ++n) {
      const int col = wn * 64 + n * 16 + lr;
      hpr[(size_t)grow * DDIM + col] = __float2half_rn(acc[n][r]);
      ps += acc[n][r] * asv[n];
      pd += acc[n][r] * adv[n];
    }
#pragma unroll
    for (int o = 1; o < 16; o <<= 1) { ps += __shfl_xor(ps, o); pd += __shfl_xor(pd, o); }
    if (lr == 0) { sred[wn][rloc] = ps; dred[wn][rloc] = pd; }
  }
  __syncthreads();
  if (t < 32) {
    s_all[(size_t)rel * NN + bm + t] = sred[0][t] + sred[1][t];
    d_all[(size_t)rel * NN + bm + t] = dred[0][t] + dred[1][t];
  }
}

// ------------- edge bias for BOTH layers, float2 loads -------------
__global__ __launch_bounds__(256)
void edge_bias_kernel(const float* __restrict__ ea, const float* __restrict__ ae0,
                      const float* __restrict__ ae1, float* __restrict__ b0,
                      float* __restrict__ b1) {
  const int wave = threadIdx.x >> 6, lane = threadIdx.x & 63;
  const int e = blockIdx.x * 4 + wave;
  if (e >= NE) return;
  const float2 v = *(const float2*)(ea + (size_t)e * DDIM + (lane << 1));
  float s0 = v.x * ae0[lane << 1] + v.y * ae0[(lane << 1) + 1];
  float s1 = v.x * ae1[lane << 1] + v.y * ae1[(lane << 1) + 1];
#pragma unroll
  for (int o = 32; o; o >>= 1) { s0 += __shfl_xor(s0, o); s1 += __shfl_xor(s1, o); }
  if (lane == 0) { b0[e] = s0; b1[e] = s1; }
}

// ------------- CSR build (3 relations batched) -------------
__global__ void count3(const int* __restrict__ d0, const int* __restrict__ d1,
                       const int* __restrict__ d2, int* __restrict__ counts) {
  const int rel = blockIdx.y;
  const int* dst = rel == 0 ? d0 : (rel == 1 ? d1 : d2);
  int* c = counts + rel * NN;
  for (int e = blockIdx.x * blockDim.x + threadIdx.x; e < NE; e += gridDim.x * blockDim.x)
    atomicAdd(&c[dst[e]], 1);
}

__global__ __launch_bounds__(1024)
void scan3(const int* __restrict__ counts_all, int* __restrict__ offs_all,
           int* __restrict__ cursor_all) {
  const int rel = blockIdx.x;
  const int* counts = counts_all + rel * NN;
  int* offs = offs_all + rel * (NN + 1);
  int* cursor = cursor_all + rel * (NN + 1);
  __shared__ int part[1024];
  const int t = threadIdx.x;
  const int CH = 40;
  const int base = t * CH;
  const int lim = min(base + CH, NN);
  int sum = 0;
  for (int i = base; i < lim; ++i) sum += counts[i];
  part[t] = sum;
  __syncthreads();
  for (int o = 1; o < 1024; o <<= 1) {
    const int v = (t >= o) ? part[t - o] : 0;
    __syncthreads();
    part[t] += v;
    __syncthreads();
  }
  int run = (t == 0) ? 0 : part[t - 1];
  for (int i = base; i < lim; ++i) { offs[i] = run; cursor[i] = run; run += counts[i]; }
  if (t == 1023) offs[NN] = part[1023];
}

__global__ void fill3(const int* __restrict__ s0, const int* __restrict__ d0,
                      const int* __restrict__ s1, const int* __restrict__ d1,
                      const int* __restrict__ s2, const int* __restrict__ d2,
                      int* __restrict__ cursor_all, int* __restrict__ csrc_all,
                      int* __restrict__ ceid0) {
  const int rel = blockIdx.y;
  const int* src = rel == 0 ? s0 : (rel == 1 ? s1 : s2);
  const int* dst = rel == 0 ? d0 : (rel == 1 ? d1 : d2);
  int* cursor = cursor_all + rel * (NN + 1);
  int* csrc = csrc_all + (size_t)rel * NE;
  for (int e = blockIdx.x * blockDim.x + threadIdx.x; e < NE; e += gridDim.x * blockDim.x) {
    const int p = atomicAdd(&cursor[dst[e]], 1);
    csrc[p] = src[e];
    if (rel == 0) ceid0[p] = e;
  }
}

// ------------- softmax-gather core (one wave, one node, one relation) -------------
__device__ __forceinline__ void gat_one(const int* __restrict__ offs,
                                        const int* __restrict__ csrc,
                                        const int* __restrict__ ceid,
                                        const float* __restrict__ ebias,
                                        const float* __restrict__ s, float dn,
                                        const __half* __restrict__ hpr, int node,
                                        float* exbuf, int* srcbuf, int lane,
                                        float& o0, float& o1) {
  const int beg = offs[node];
  int cnt = offs[node + 1] - beg;
  if (cnt > CAP) cnt = CAP;
  if (cnt == 0) return;
  __threadfence_block();
  float m = -1e30f;
  for (int i = lane; i < cnt; i += 64) {
    const int sn = csrc[beg + i];
    float logit = s[sn] + dn;
    if (ebias) logit += ebias[ceid[beg + i]];
    const float e = logit >= 0.f ? logit : 0.2f * logit;
    exbuf[i] = e;
    srcbuf[i] = sn;
    m = fmaxf(m, e);
  }
#pragma unroll
  for (int o = 32; o; o >>= 1) m = fmaxf(m, __shfl_xor(m, o));
  float ssum = 0.f;
  for (int i = lane; i < cnt; i += 64) {
    const float ex = __expf(exbuf[i] - m);
    exbuf[i] = ex;
    ssum += ex;
  }
#pragma unroll
  for (int o = 32; o; o >>= 1) ssum += __shfl_xor(ssum, o);
  const float inv = 1.f / (ssum + 1e-16f);
  __threadfence_block();
  const int c = lane << 1;
  float n0 = 0.f, n1 = 0.f;
  int i = 0;
  for (; i + 2 <= cnt; i += 2) {
    const float w0 = exbuf[i], w1 = exbuf[i + 1];
    const float2 v0 = __half22float2(*(const __half2*)(hpr + (size_t)srcbuf[i] * DDIM + c));
    const float2 v1 = __half22float2(*(const __half2*)(hpr + (size_t)srcbuf[i + 1] * DDIM + c));
    n0 += w0 * v0.x + w1 * v1.x;
    n1 += w0 * v0.y + w1 * v1.y;
  }
  for (; i < cnt; ++i) {
    const float w = exbuf[i];
    const float2 v = __half22float2(*(const __half2*)(hpr + (size_t)srcbuf[i] * DDIM + c));
    n0 += w * v.x;
    n1 += w * v.y;
  }
  const float v0 = n0 * inv, v1 = n1 * inv;
  o0 += (v0 > 0.f ? v0 : expm1f(v0));
  o1 += (v1 > 0.f ? v1 : expm1f(v1));
}

// ------------- fused aggregation: all 40000 nodes in one launch -------------
__global__ __launch_bounds__(256)
void agg_all(const int* __restrict__ offs_all, const int* __restrict__ csrc_all,
             const int* __restrict__ ceid0, const float* __restrict__ ebias,
             const float* __restrict__ s_all, const float* __restrict__ d_all,
             const __half* __restrict__ hp16, float* __restrict__ outf,
             short* __restrict__ ohh, short* __restrict__ ohl, int write_f32) {
  __shared__ float exbuf[4][CAP];
  __shared__ int   srcbuf[4][CAP];
  const int wave = threadIdx.x >> 6, lane = threadIdx.x & 63;
  const int node = blockIdx.x * 4 + wave;
  float o0 = 0.f, o1 = 0.f;
  if (node < NDRUG) {
    gat_one(offs_all, csrc_all, ceid0, ebias, s_all, d_all[node],
            hp16, node, exbuf[wave], srcbuf[wave], lane, o0, o1);
  } else {
#pragma unroll
    for (int rel = 1; rel <= 2; ++rel) {
      gat_one(offs_all + rel * (NN + 1), csrc_all + (size_t)rel * NE, nullptr, nullptr,
              s_all + (size_t)rel * NN, d_all[(size_t)rel * NN + node],
              hp16 + (size_t)rel * NN * DDIM, node, exbuf[wave], srcbuf[wave], lane, o0, o1);
    }
  }
  o0 *= (1.f / 3.f);
  o1 *= (1.f / 3.f);
  const int c = lane << 1;
  if (write_f32) {
    *(float2*)(outf + (size_t)node * DDIM + c) = make_float2(o0, o1);
  } else {
    short h0, l0, h1, l1;
    split1(o0, h0, l0);
    split1(o1, h1, l1);
    *(short2*)(ohh + (size_t)node * DDIM + c) = make_short2(h0, h1);
    *(short2*)(ohl + (size_t)node * DDIM + c) = make_short2(l0, l1);
  }
}

extern "C" void kernel_launch(void* const* d_in, const int* in_sizes, int n_in,
                              void* d_out, int out_size, void* d_ws, size_t ws_size,
                              hipStream_t stream) {
  const float* x_drug    = (const float*)d_in[0];
  const float* x_target  = (const float*)d_in[1];
  const float* W_drug    = (const float*)d_in[2];
  const float* b_drug    = (const float*)d_in[3];
  const float* W_target  = (const float*)d_in[4];
  const float* b_target  = (const float*)d_in[5];
  const float* W_gat     = (const float*)d_in[6];
  const float* a_src     = (const float*)d_in[7];
  const float* a_dst     = (const float*)d_in[8];
  const float* a_edge    = (const float*)d_in[9];
  const float* edge_attr = (const float*)d_in[10];
  const int*   e_dd      = (const int*)d_in[11];
  const int*   e_dt      = (const int*)d_in[12];
  const int*   e_tt      = (const int*)d_in[13];
  float* out = (float*)d_out;

  char* ws = (char*)d_ws;
  size_t off = 0;
  auto alloc = [&](size_t b) -> void* {
    void* p = ws + off;
    off += (b + 255) & ~(size_t)255;
    return p;
  };
  __half* hp16  = (__half*)alloc((size_t)3 * NN * DDIM * 2);
  short* hhA    = (short*)alloc((size_t)NN * DDIM * 2);
  short* hlA    = (short*)alloc((size_t)NN * DDIM * 2);
  short* hhB    = (short*)alloc((size_t)NN * DDIM * 2);
  short* hlB    = (short*)alloc((size_t)NN * DDIM * 2);
  float* s_all  = (float*)alloc((size_t)3 * NN * 4);
  float* d_allb = (float*)alloc((size_t)3 * NN * 4);
  float* bias0  = (float*)alloc((size_t)NE * 4);
  float* bias1  = (float*)alloc((size_t)NE * 4);
  int* counts   = (int*)alloc((size_t)3 * NN * 4);
  int* offs_all = (int*)alloc((size_t)3 * (NN + 1) * 4);
  int* cur_all  = (int*)alloc((size_t)3 * (NN + 1) * 4);
  int* csrc_all = (int*)alloc((size_t)3 * NE * 4);
  int* ceid0    = (int*)alloc((size_t)NE * 4);
  short* pwd_h  = (short*)alloc((size_t)2048 * 128 * 2);
  short* pwd_l  = (short*)alloc((size_t)2048 * 128 * 2);
  short* pwt_h  = (short*)alloc((size_t)1280 * 128 * 2);
  short* pwt_l  = (short*)alloc((size_t)1280 * 128 * 2);
  short* pwg_h  = (short*)alloc((size_t)6 * 128 * 128 * 2);
  short* pwg_l  = (short*)alloc((size_t)6 * 128 * 128 * 2);

  // 0) weight prep: packed fragment tiles, hi/lo split
  prep_pack<<<dim3(1024, 1), 256, 0, stream>>>(W_drug, pwd_h, pwd_l, 2048);
  prep_pack<<<dim3(640, 1), 256, 0, stream>>>(W_target, pwt_h, pwt_l, 1280);
  prep_pack<<<dim3(64, 6), 256, 0, stream>>>(W_gat, pwg_h, pwg_l, 128);

  // 1) projections -> h hi/lo planes (2-phase glds, BM=32, 4 blocks/CU)
  gemm_proj<<<1250, 256, 0, stream>>>(x_drug, pwd_h, pwd_l, b_drug,
                                      x_target, pwt_h, pwt_l, b_target, hhA, hlA);

  // 2) edge biases for both layers (one 256MB pass)
  edge_bias_kernel<<<NE / 4, 256, 0, stream>>>(edge_attr, a_edge, a_edge + DDIM,
                                               bias0, bias1);
  // 3) CSR build (3 relations, reused by both layers)
  hipMemsetAsync(counts, 0, (size_t)3 * NN * 4, stream);
  count3<<<dim3(170, 3), 256, 0, stream>>>(e_dd + NE, e_dt + NE, e_tt + NE, counts);
  scan3<<<3, 1024, 0, stream>>>(counts, offs_all, cur_all);
  fill3<<<dim3(170, 3), 256, 0, stream>>>(e_dd, e_dd + NE, e_dt, e_dt + NE,
                                          e_tt, e_tt + NE, cur_all, csrc_all, ceid0);

  // 4) two GAT layers
  // layer 0
  gemm_gat<<<dim3(1250, 3), 256, 0, stream>>>(hhA, hlA, pwg_h, pwg_l,
                                              a_src, a_dst, hp16, s_all, d_allb);
  agg_all<<<NN / 4, 256, 0, stream>>>(offs_all, csrc_all, ceid0, bias0,
                                      s_all, d_allb, hp16, nullptr, hhB, hlB, 0);
  // layer 1
  gemm_gat<<<dim3(1250, 3), 256, 0, stream>>>(hhB, hlB,
                                              pwg_h + (size_t)3 * DDIM * DDIM,
                                              pwg_l + (size_t)3 * DDIM * DDIM,
                                              a_src + 3 * DDIM, a_dst + 3 * DDIM,
                                              hp16, s_all, d_allb);
  agg_all<<<NN / 4, 256, 0, stream>>>(offs_all, csrc_all, ceid0, bias1,
                                      s_all, d_allb, hp16, out, nullptr, nullptr, 1);
}

// Round 11
// 704.951 us; speedup vs baseline: 1.4373x; 1.0281x over previous
//
#include <hip/hip_runtime.h>
#include <hip/hip_fp16.h>
#include <hip/hip_bf16.h>

#define NDRUG 20000
#define NTGT  20000
#define NN    40000
#define NE    500000
#define DDIM  128
#define CAP   96
#define AS1 __attribute__((address_space(1)))
#define AS3 __attribute__((address_space(3)))

typedef __attribute__((ext_vector_type(4))) float f32x4;
typedef __attribute__((ext_vector_type(8))) short s16x8;
typedef __attribute__((ext_vector_type(4))) unsigned u32x4;

__device__ inline unsigned short bf_rn(float x) {
  unsigned u = __float_as_uint(x);
  return (unsigned short)((u + 0x7FFFu + ((u >> 16) & 1u)) >> 16);
}
// scalar fp32 -> bf16 hi (RTN) + lo (RTN residual) — used in prep & agg epilogue
__device__ __forceinline__ void split1(float x, short& h, short& l) {
  const unsigned u = __float_as_uint(x);
  const unsigned hu = (u + 0x7FFFu + ((u >> 16) & 1u)) & 0xFFFF0000u;
  h = (short)(hu >> 16);
  l = (short)bf_rn(x - __uint_as_float(hu));
}
// packed pair split via v_cvt_pk_bf16_f32 (RTN): ~3 VALU ops/element
__device__ __forceinline__ void split_pk(float x0, float x1, unsigned& hp, unsigned& lp) {
  __hip_bfloat162 h2 = __float22bfloat162_rn(make_float2(x0, x1));
  unsigned hu; __builtin_memcpy(&hu, &h2, 4);
  const float f0 = __uint_as_float(hu << 16);
  const float f1 = __uint_as_float(hu & 0xFFFF0000u);
  __hip_bfloat162 l2 = __float22bfloat162_rn(make_float2(x0 - f0, x1 - f1));
  unsigned lu; __builtin_memcpy(&lu, &l2, 4);
  hp = hu; lp = lu;
}
__device__ __forceinline__ void cvt8_pk(const float4 a, const float4 b, s16x8& h, s16x8& l) {
  unsigned h0, h1, h2, h3, l0, l1, l2, l3;
  split_pk(a.x, a.y, h0, l0);
  split_pk(a.z, a.w, h1, l1);
  split_pk(b.x, b.y, h2, l2);
  split_pk(b.z, b.w, h3, l3);
  u32x4 hu = {h0, h1, h2, h3};
  u32x4 lu = {l0, l1, l2, l3};
  h = __builtin_bit_cast(s16x8, hu);
  l = __builtin_bit_cast(s16x8, lu);
}
__device__ __forceinline__ void glds16(const void* g, void* l) {
  __builtin_amdgcn_global_load_lds((const AS1 unsigned*)g, (AS3 unsigned*)l, 16, 0, 0);
}
__device__ __forceinline__ f32x4 mfma(const s16x8& a, const s16x8& b, const f32x4& c) {
  return __builtin_amdgcn_mfma_f32_16x16x32_bf16(a, b, c, 0, 0, 0);
}
// bank-spreading involution on chunk indices (16B chunks): read 2-way max
__device__ __forceinline__ int swz(int c) { return c ^ ((c >> 3) & 7); }

// ------- weight prep: W [K][128] fp32 -> packed+swizzled fragment tiles, hi/lo bf16 ----
// dest layout: [K/32 tiles][512 chunks][8 shorts]; dest chunk d holds logical chunk
// c = swz(d), c = col*4 + kg, element j = W[kt*32 + kg*8 + j][col].
__global__ void prep_pack(const float* __restrict__ W, short* __restrict__ ph,
                          short* __restrict__ pl, int K) {
  const size_t mat = (size_t)blockIdx.y * K * 128;
  const int idx = blockIdx.x * blockDim.x + threadIdx.x;
  if (idx >= K * 128) return;
  const int kt = idx >> 12, r = idx & 4095;
  const int dchunk = r >> 3, j = r & 7;
  const int c = swz(dchunk);
  const int col = c >> 2, kg = c & 3;
  const int k = kt * 32 + kg * 8 + j;
  short h, l;
  split1(W[mat + (size_t)k * 128 + col], h, l);
  ph[mat + idx] = h;
  pl[mat + idx] = l;
}

// ---------------- 2-phase glds projection GEMM, BM=64 BN=128 BK=32 ----------------
// 48KB LDS -> 3 blocks/CU; grid 626. 4 waves, each owns 16 rows x 128 cols:
// 1 cvt8 + 16 B-frag reads + 24 MFMA per K-step.
__global__ __launch_bounds__(256)
void gemm_proj(const float* __restrict__ xd, const short* __restrict__ pdh,
               const short* __restrict__ pdl, const float* __restrict__ bd,
               const float* __restrict__ xt, const short* __restrict__ pth,
               const short* __restrict__ ptl, const float* __restrict__ bt,
               short* __restrict__ hh, short* __restrict__ hl) {
  __shared__ float Af[2][64 * 32];      // 8KB x2
  __shared__ short Bf[2][2][4096];      // [buf][plane] 8KB x4 = 32KB

  int b = blockIdx.x;
  const float* A; const short* BH; const short* BL; const float* bias;
  int M, K, rowbase;
  if (b < 313) { A = xd; BH = pdh; BL = pdl; bias = bd; M = NDRUG; K = 2048; rowbase = 0; }
  else { b -= 313; A = xt; BH = pth; BL = ptl; bias = bt; M = NTGT; K = 1280; rowbase = NDRUG; }
  const int bm = b * 64;
  const int t = threadIdx.x, w = t >> 6, lane = t & 63;
  const int lr = lane & 15, kg = lane >> 4;
  const int steps = K >> 5;

  // A staging: 512 chunks(16B) of the 64x32 fp32 tile; chunk d: row=d>>3, cpos=d&7,
  // source col-group csrc = cpos ^ (row&7) (pre-swizzled source, linear dest).
  const int ad0 = (w << 6) + lane, ad1 = ad0 + 256;
  const int ar0 = ad0 >> 3, ar1 = ad1 >> 3;
  const int ac0 = (ad0 & 7) ^ (ar0 & 7), ac1 = (ad1 & 7) ^ (ar1 & 7);
  int gr0 = bm + ar0; if (gr0 >= M) gr0 = M - 1;
  int gr1 = bm + ar1; if (gr1 >= M) gr1 = M - 1;
  const float* asrc0 = A + (size_t)gr0 * K + ac0 * 4;
  const float* asrc1 = A + (size_t)gr1 * K + ac1 * 4;
  const int bd0 = (w << 6) + lane, bd1 = bd0 + 256;

  f32x4 acc[8] = {};

  auto stage = [&](int buf, int kt) {
    const int kk = kt << 5;
    glds16(asrc0 + kk, &Af[buf][(w << 6) * 4]);
    glds16(asrc1 + kk, &Af[buf][(256 + (w << 6)) * 4]);
    const size_t bo = (size_t)kt * 4096;
    glds16(BH + bo + bd0 * 8, &Bf[buf][0][(w << 6) * 8]);
    glds16(BH + bo + bd1 * 8, &Bf[buf][0][(256 + (w << 6)) * 8]);
    glds16(BL + bo + bd0 * 8, &Bf[buf][1][(w << 6) * 8]);
    glds16(BL + bo + bd1 * 8, &Bf[buf][1][(256 + (w << 6)) * 8]);
  };

  const int arow = (w << 4) + lr;
  const int ap0 = (arow * 8 + ((kg * 2) ^ (arow & 7))) * 4;
  const int ap1 = (arow * 8 + ((kg * 2 + 1) ^ (arow & 7))) * 4;

  auto compute = [&](int buf) {
    const float4 va = *(const float4*)&Af[buf][ap0];
    const float4 vb = *(const float4*)&Af[buf][ap1];
    s16x8 ah, al;
    cvt8_pk(va, vb, ah, al);
#pragma unroll
    for (int n = 0; n < 8; ++n) {
      const int c = ((n * 16 + lr) << 2) + kg;
      const int pos = swz(c) << 3;
      const s16x8 bh = *(const s16x8*)&Bf[buf][0][pos];
      const s16x8 bl = *(const s16x8*)&Bf[buf][1][pos];
      acc[n] = mfma(ah, bh, acc[n]);
      acc[n] = mfma(ah, bl, acc[n]);
      acc[n] = mfma(al, bh, acc[n]);
    }
  };

  stage(0, 0);
  __syncthreads();
  int cur = 0;
  for (int kt = 0; kt < steps - 1; ++kt) {
    stage(cur ^ 1, kt + 1);
    compute(cur);
    __syncthreads();
    cur ^= 1;
  }
  compute(cur);

#pragma unroll
  for (int n = 0; n < 8; ++n) {
    const int col = n * 16 + lr;
    const float bv = bias[col];
#pragma unroll
    for (int r = 0; r < 4; ++r) {
      const int row = bm + (w << 4) + kg * 4 + r;
      if (row < M) {
        short h, l;
        split1(acc[n][r] + bv, h, l);
        hh[(size_t)(rowbase + row) * DDIM + col] = h;
        hl[(size_t)(rowbase + row) * DDIM + col] = l;
      }
    }
  }
}

// ---------------- 2-phase glds GAT GEMM + fused s/d, BM=64 BN=128 ----------------
// A = h bf16 hi/lo planes [NN][128] (staged with swz via pre-swizzled source);
// B packed+swizzled. grid (625, 3); K=128 (4 steps). 48KB LDS.
__global__ __launch_bounds__(256)
void gemm_gat(const short* __restrict__ ahh, const short* __restrict__ ahl,
              const short* __restrict__ PH3, const short* __restrict__ PL3,
              const float* __restrict__ asrc3, const float* __restrict__ adst3,
              __half* __restrict__ hp16, float* __restrict__ s_all,
              float* __restrict__ d_all) {
  __shared__ short Apl[2][2][2048];     // [buf][plane] 4KB x4 = 16KB
  __shared__ short Bf[2][2][4096];      // 32KB

  const int rel = blockIdx.y;
  const int bm = blockIdx.x * 64;
  const short* BH = PH3 + (size_t)rel * DDIM * DDIM;
  const short* BL = PL3 + (size_t)rel * DDIM * DDIM;
  const int t = threadIdx.x, w = t >> 6, lane = t & 63;
  const int lr = lane & 15, kg = lane >> 4;

  // A staging: 256 chunks/plane; plane = w>>1; dest chunk = (w&1)*64+lane (+128).
  // dest linear; source logical chunk swz(d): row = c>>2, cpos = c&3.
  const int apn = w >> 1;
  const short* aplane = apn ? ahl : ahh;
  const int ad0 = ((w & 1) << 6) + lane, ad1 = ad0 + 128;
  const int ac0 = swz(ad0), ac1 = swz(ad1);
  const short* asrc0 = aplane + (size_t)(bm + (ac0 >> 2)) * DDIM + (ac0 & 3) * 8;
  const short* asrc1 = aplane + (size_t)(bm + (ac1 >> 2)) * DDIM + (ac1 & 3) * 8;
  const int bd0 = (w << 6) + lane, bd1 = bd0 + 256;

  f32x4 acc[8] = {};

  auto stage = [&](int buf, int kt) {
    const int kk = kt << 5;
    glds16(asrc0 + kk, &Apl[buf][apn][ad0 * 8]);
    glds16(asrc1 + kk, &Apl[buf][apn][ad1 * 8]);
    const size_t bo = (size_t)kt * 4096;
    glds16(BH + bo + bd0 * 8, &Bf[buf][0][(w << 6) * 8]);
    glds16(BH + bo + bd1 * 8, &Bf[buf][0][(256 + (w << 6)) * 8]);
    glds16(BL + bo + bd0 * 8, &Bf[buf][1][(w << 6) * 8]);
    glds16(BL + bo + bd1 * 8, &Bf[buf][1][(256 + (w << 6)) * 8]);
  };

  const int arow = (w << 4) + lr;
  const int apos = swz((arow << 2) + kg) << 3;

  auto compute = [&](int buf) {
    const s16x8 ah = *(const s16x8*)&Apl[buf][0][apos];
    const s16x8 al = *(const s16x8*)&Apl[buf][1][apos];
#pragma unroll
    for (int n = 0; n < 8; ++n) {
      const int c = ((n * 16 + lr) << 2) + kg;
      const int pos = swz(c) << 3;
      const s16x8 bh = *(const s16x8*)&Bf[buf][0][pos];
      const s16x8 bl = *(const s16x8*)&Bf[buf][1][pos];
      acc[n] = mfma(ah, bh, acc[n]);
      acc[n] = mfma(ah, bl, acc[n]);
      acc[n] = mfma(al, bh, acc[n]);
    }
  };

  stage(0, 0);
  __syncthreads();
  int cur = 0;
  for (int kt = 0; kt < 3; ++kt) {
    stage(cur ^ 1, kt + 1);
    compute(cur);
    __syncthreads();
    cur ^= 1;
  }
  compute(cur);

  // hp16 write + fused s/d (full row per wave -> no cross-wave reduction)
  __half* hpr = hp16 + (size_t)rel * NN * DDIM;
  float asv[8], adv[8];
#pragma unroll
  for (int n = 0; n < 8; ++n) {
    asv[n] = asrc3[rel * DDIM + n * 16 + lr];
    adv[n] = adst3[rel * DDIM + n * 16 + lr];
  }
#pragma unroll
  for (int r = 0; r < 4; ++r) {
    const int row = bm + (w << 4) + kg * 4 + r;
    float ps = 0.f, pd = 0.f;
#pragma unroll
    for (int n = 0; n < 8; ++n) {
      hpr[(size_t)row * DDIM + n * 16 + lr] = __float2half_rn(acc[n][r]);
      ps += acc[n][r] * asv[n];
      pd += acc[n][r] * adv[n];
    }
#pragma unroll
    for (int o = 1; o < 16; o <<= 1) { ps += __shfl_xor(ps, o); pd += __shfl_xor(pd, o); }
    if (lr == 0) {
      s_all[(size_t)rel * NN + row] = ps;
      d_all[(size_t)rel * NN + row] = pd;
    }
  }
}

// ------------- edge bias for BOTH layers, float2 loads -------------
__global__ __launch_bounds__(256)
void edge_bias_kernel(const float* __restrict__ ea, const float* __restrict__ ae0,
                      const float* __restrict__ ae1, float* __restrict__ b0,
                      float* __restrict__ b1) {
  const int wave = threadIdx.x >> 6, lane = threadIdx.x & 63;
  const int e = blockIdx.x * 4 + wave;
  if (e >= NE) return;
  const float2 v = *(const float2*)(ea + (size_t)e * DDIM + (lane << 1));
  float s0 = v.x * ae0[lane << 1] + v.y * ae0[(lane << 1) + 1];
  float s1 = v.x * ae1[lane << 1] + v.y * ae1[(lane << 1) + 1];
#pragma unroll
  for (int o = 32; o; o >>= 1) { s0 += __shfl_xor(s0, o); s1 += __shfl_xor(s1, o); }
  if (lane == 0) { b0[e] = s0; b1[e] = s1; }
}

// ------------- CSR build (3 relations batched) -------------
__global__ void count3(const int* __restrict__ d0, const int* __restrict__ d1,
                       const int* __restrict__ d2, int* __restrict__ counts) {
  const int rel = blockIdx.y;
  const int* dst = rel == 0 ? d0 : (rel == 1 ? d1 : d2);
  int* c = counts + rel * NN;
  for (int e = blockIdx.x * blockDim.x + threadIdx.x; e < NE; e += gridDim.x * blockDim.x)
    atomicAdd(&c[dst[e]], 1);
}

__global__ __launch_bounds__(1024)
void scan3(const int* __restrict__ counts_all, int* __restrict__ offs_all,
           int* __restrict__ cursor_all) {
  const int rel = blockIdx.x;
  const int* counts = counts_all + rel * NN;
  int* offs = offs_all + rel * (NN + 1);
  int* cursor = cursor_all + rel * (NN + 1);
  __shared__ int part[1024];
  const int t = threadIdx.x;
  const int CH = 40;
  const int base = t * CH;
  const int lim = min(base + CH, NN);
  int sum = 0;
  for (int i = base; i < lim; ++i) sum += counts[i];
  part[t] = sum;
  __syncthreads();
  for (int o = 1; o < 1024; o <<= 1) {
    const int v = (t >= o) ? part[t - o] : 0;
    __syncthreads();
    part[t] += v;
    __syncthreads();
  }
  int run = (t == 0) ? 0 : part[t - 1];
  for (int i = base; i < lim; ++i) { offs[i] = run; cursor[i] = run; run += counts[i]; }
  if (t == 1023) offs[NN] = part[1023];
}

__global__ void fill3(const int* __restrict__ s0, const int* __restrict__ d0,
                      const int* __restrict__ s1, const int* __restrict__ d1,
                      const int* __restrict__ s2, const int* __restrict__ d2,
                      int* __restrict__ cursor_all, int* __restrict__ csrc_all,
                      int* __restrict__ ceid0) {
  const int rel = blockIdx.y;
  const int* src = rel == 0 ? s0 : (rel == 1 ? s1 : s2);
  const int* dst = rel == 0 ? d0 : (rel == 1 ? d1 : d2);
  int* cursor = cursor_all + rel * (NN + 1);
  int* csrc = csrc_all + (size_t)rel * NE;
  for (int e = blockIdx.x * blockDim.x + threadIdx.x; e < NE; e += gridDim.x * blockDim.x) {
    const int p = atomicAdd(&cursor[dst[e]], 1);
    csrc[p] = src[e];
    if (rel == 0) ceid0[p] = e;
  }
}

// ------------- softmax-gather core (one wave, one node, one relation) -------------
__device__ __forceinline__ void gat_one(const int* __restrict__ offs,
                                        const int* __restrict__ csrc,
                                        const int* __restrict__ ceid,
                                        const float* __restrict__ ebias,
                                        const float* __restrict__ s, float dn,
                                        const __half* __restrict__ hpr, int node,
                                        float* exbuf, int* srcbuf, int lane,
                                        float& o0, float& o1) {
  const int beg = offs[node];
  int cnt = offs[node + 1] - beg;
  if (cnt > CAP) cnt = CAP;
  if (cnt == 0) return;
  __threadfence_block();
  float m = -1e30f;
  for (int i = lane; i < cnt; i += 64) {
    const int sn = csrc[beg + i];
    float logit = s[sn] + dn;
    if (ebias) logit += ebias[ceid[beg + i]];
    const float e = logit >= 0.f ? logit : 0.2f * logit;
    exbuf[i] = e;
    srcbuf[i] = sn;
    m = fmaxf(m, e);
  }
#pragma unroll
  for (int o = 32; o; o >>= 1) m = fmaxf(m, __shfl_xor(m, o));
  float ssum = 0.f;
  for (int i = lane; i < cnt; i += 64) {
    const float ex = __expf(exbuf[i] - m);
    exbuf[i] = ex;
    ssum += ex;
  }
#pragma unroll
  for (int o = 32; o; o >>= 1) ssum += __shfl_xor(ssum, o);
  const float inv = 1.f / (ssum + 1e-16f);
  __threadfence_block();
  const int c = lane << 1;
  float n0 = 0.f, n1 = 0.f;
  int i = 0;
  for (; i + 2 <= cnt; i += 2) {
    const float w0 = exbuf[i], w1 = exbuf[i + 1];
    const float2 v0 = __half22float2(*(const __half2*)(hpr + (size_t)srcbuf[i] * DDIM + c));
    const float2 v1 = __half22float2(*(const __half2*)(hpr + (size_t)srcbuf[i + 1] * DDIM + c));
    n0 += w0 * v0.x + w1 * v1.x;
    n1 += w0 * v0.y + w1 * v1.y;
  }
  for (; i < cnt; ++i) {
    const float w = exbuf[i];
    const float2 v = __half22float2(*(const __half2*)(hpr + (size_t)srcbuf[i] * DDIM + c));
    n0 += w * v.x;
    n1 += w * v.y;
  }
  const float v0 = n0 * inv, v1 = n1 * inv;
  o0 += (v0 > 0.f ? v0 : expm1f(v0));
  o1 += (v1 > 0.f ? v1 : expm1f(v1));
}

// ------------- fused aggregation: all 40000 nodes in one launch -------------
__global__ __launch_bounds__(256)
void agg_all(const int* __restrict__ offs_all, const int* __restrict__ csrc_all,
             const int* __restrict__ ceid0, const float* __restrict__ ebias,
             const float* __restrict__ s_all, const float* __restrict__ d_all,
             const __half* __restrict__ hp16, float* __restrict__ outf,
             short* __restrict__ ohh, short* __restrict__ ohl, int write_f32) {
  __shared__ float exbuf[4][CAP];
  __shared__ int   srcbuf[4][CAP];
  const int wave = threadIdx.x >> 6, lane = threadIdx.x & 63;
  const int node = blockIdx.x * 4 + wave;
  float o0 = 0.f, o1 = 0.f;
  if (node < NDRUG) {
    gat_one(offs_all, csrc_all, ceid0, ebias, s_all, d_all[node],
            hp16, node, exbuf[wave], srcbuf[wave], lane, o0, o1);
  } else {
#pragma unroll
    for (int rel = 1; rel <= 2; ++rel) {
      gat_one(offs_all + rel * (NN + 1), csrc_all + (size_t)rel * NE, nullptr, nullptr,
              s_all + (size_t)rel * NN, d_all[(size_t)rel * NN + node],
              hp16 + (size_t)rel * NN * DDIM, node, exbuf[wave], srcbuf[wave], lane, o0, o1);
    }
  }
  o0 *= (1.f / 3.f);
  o1 *= (1.f / 3.f);
  const int c = lane << 1;
  if (write_f32) {
    *(float2*)(outf + (size_t)node * DDIM + c) = make_float2(o0, o1);
  } else {
    short h0, l0, h1, l1;
    split1(o0, h0, l0);
    split1(o1, h1, l1);
    *(short2*)(ohh + (size_t)node * DDIM + c) = make_short2(h0, h1);
    *(short2*)(ohl + (size_t)node * DDIM + c) = make_short2(l0, l1);
  }
}

extern "C" void kernel_launch(void* const* d_in, const int* in_sizes, int n_in,
                              void* d_out, int out_size, void* d_ws, size_t ws_size,
                              hipStream_t stream) {
  const float* x_drug    = (const float*)d_in[0];
  const float* x_target  = (const float*)d_in[1];
  const float* W_drug    = (const float*)d_in[2];
  const float* b_drug    = (const float*)d_in[3];
  const float* W_target  = (const float*)d_in[4];
  const float* b_target  = (const float*)d_in[5];
  const float* W_gat     = (const float*)d_in[6];
  const float* a_src     = (const float*)d_in[7];
  const float* a_dst     = (const float*)d_in[8];
  const float* a_edge    = (const float*)d_in[9];
  const float* edge_attr = (const float*)d_in[10];
  const int*   e_dd      = (const int*)d_in[11];
  const int*   e_dt      = (const int*)d_in[12];
  const int*   e_tt      = (const int*)d_in[13];
  float* out = (float*)d_out;

  char* ws = (char*)d_ws;
  size_t off = 0;
  auto alloc = [&](size_t b) -> void* {
    void* p = ws + off;
    off += (b + 255) & ~(size_t)255;
    return p;
  };
  __half* hp16  = (__half*)alloc((size_t)3 * NN * DDIM * 2);
  short* hhA    = (short*)alloc((size_t)NN * DDIM * 2);
  short* hlA    = (short*)alloc((size_t)NN * DDIM * 2);
  short* hhB    = (short*)alloc((size_t)NN * DDIM * 2);
  short* hlB    = (short*)alloc((size_t)NN * DDIM * 2);
  float* s_all  = (float*)alloc((size_t)3 * NN * 4);
  float* d_allb = (float*)alloc((size_t)3 * NN * 4);
  float* bias0  = (float*)alloc((size_t)NE * 4);
  float* bias1  = (float*)alloc((size_t)NE * 4);
  int* counts   = (int*)alloc((size_t)3 * NN * 4);
  int* offs_all = (int*)alloc((size_t)3 * (NN + 1) * 4);
  int* cur_all  = (int*)alloc((size_t)3 * (NN + 1) * 4);
  int* csrc_all = (int*)alloc((size_t)3 * NE * 4);
  int* ceid0    = (int*)alloc((size_t)NE * 4);
  short* pwd_h  = (short*)alloc((size_t)2048 * 128 * 2);
  short* pwd_l  = (short*)alloc((size_t)2048 * 128 * 2);
  short* pwt_h  = (short*)alloc((size_t)1280 * 128 * 2);
  short* pwt_l  = (short*)alloc((size_t)1280 * 128 * 2);
  short* pwg_h  = (short*)alloc((size_t)6 * 128 * 128 * 2);
  short* pwg_l  = (short*)alloc((size_t)6 * 128 * 128 * 2);

  // 0) weight prep: packed+swizzled fragment tiles, hi/lo split
  prep_pack<<<dim3(1024, 1), 256, 0, stream>>>(W_drug, pwd_h, pwd_l, 2048);
  prep_pack<<<dim3(640, 1), 256, 0, stream>>>(W_target, pwt_h, pwt_l, 1280);
  prep_pack<<<dim3(64, 6), 256, 0, stream>>>(W_gat, pwg_h, pwg_l, 128);

  // 1) projections -> h hi/lo planes (2-phase glds, BM=64, 3 blocks/CU)
  gemm_proj<<<626, 256, 0, stream>>>(x_drug, pwd_h, pwd_l, b_drug,
                                     x_target, pwt_h, pwt_l, b_target, hhA, hlA);

  // 2) edge biases for both layers (one 256MB pass)
  edge_bias_kernel<<<NE / 4, 256, 0, stream>>>(edge_attr, a_edge, a_edge + DDIM,
                                               bias0, bias1);
  // 3) CSR build (3 relations, reused by both layers)
  hipMemsetAsync(counts, 0, (size_t)3 * NN * 4, stream);
  count3<<<dim3(170, 3), 256, 0, stream>>>(e_dd + NE, e_dt + NE, e_tt + NE, counts);
  scan3<<<3, 1024, 0, stream>>>(counts, offs_all, cur_all);
  fill3<<<dim3(170, 3), 256, 0, stream>>>(e_dd, e_dd + NE, e_dt, e_dt + NE,
                                          e_tt, e_tt + NE, cur_all, csrc_all, ceid0);

  // 4) two GAT layers
  // layer 0
  gemm_gat<<<dim3(625, 3), 256, 0, stream>>>(hhA, hlA, pwg_h, pwg_l,
                                             a_src, a_dst, hp16, s_all, d_allb);
  agg_all<<<NN / 4, 256, 0, stream>>>(offs_all, csrc_all, ceid0, bias0,
                                      s_all, d_allb, hp16, nullptr, hhB, hlB, 0);
  // layer 1
  gemm_gat<<<dim3(625, 3), 256, 0, stream>>>(hhB, hlB,
                                             pwg_h + (size_t)3 * DDIM * DDIM,
                                             pwg_l + (size_t)3 * DDIM * DDIM,
                                             a_src + 3 * DDIM, a_dst + 3 * DDIM,
                                             hp16, s_all, d_allb);
  agg_all<<<NN / 4, 256, 0, stream>>>(offs_all, csrc_all, ceid0, bias1,
                                      s_all, d_allb, hp16, out, nullptr, nullptr, 1);
}